// Round 9
// baseline (758.201 us; speedup 1.0000x reference)
//
#include <hip/hip_runtime.h>
#include <hip/hip_bf16.h>

#define N_NODES   50000
#define N_EDGES   600000
#define HID       128
#define N_LAYERS  4
#define N_GRAPHS  128
#define N_CLASSES 10
#define BN_EPS    1e-5f

#define TILE_R 64           // 16 ty-groups x 4 interleaved rows (r = ty + 16i)
#define KC     32
#define RSPLIT 8
#define SCAN_B 196          // ceil(50000/256)
#define GEMM_GRID ((N_NODES + TILE_R - 1) / TILE_R)   // 782

// ---------------- workspace layout (in 4-byte elements) ----------------
#define OFF_WMT   0u                         // 5 * 16384 masked+transposed weights [k][c]
#define OFF_H     81920u                     // 50000*128
#define OFF_Z     (OFF_H   + 6400000u)
#define OFF_AGG   (OFF_Z   + 6400000u)       // aggregate output [50000][128]
#define OFF_ZERO  (OFF_AGG + 6400000u)       // start of zero-initialized region
#define OFF_CSUM  OFF_ZERO                   // [4][2][128] = 1024 f
#define OFF_SUMS  (OFF_CSUM + 1024u)         // [128][128]  = 16384 f
#define OFF_DEG   (OFF_SUMS + 16384u)        // [50000] int
#define ZERO_N    (1024u + 16384u + 50000u)  // 67408 elements
#define OFF_OFFS  (OFF_ZERO + ZERO_N)        // [50001] int (padded to 50004)
#define OFF_POS   (OFF_OFFS + 50004u)        // [50000] int
#define OFF_ESRC  (OFF_POS  + 50000u)        // [600000] int
#define OFF_GST   (OFF_ESRC + 600000u)       // [129] int graph boundaries (pad 132)
#define OFF_BSUM  (OFF_GST  + 132u)          // [196] int block sums
#define OFF_TOT   (OFF_BSUM + 196u)          // [1] int total

// preamble block ranges
#define PRE_ZB 264                    // zero blocks (67408 -> 264*256)
#define PRE_WB 320                    // wmask blocks (81920)
#define PRE_BB 196                    // bounds blocks (50000)

// fused preamble: zero workspace region | masked+transposed weights | graph bounds
__global__ __launch_bounds__(256) void preamble_kernel(
    int* __restrict__ zbase,
    const float* __restrict__ We, const float* __restrict__ Me,
    const float* __restrict__ Wl, const float* __restrict__ Ml,
    float* __restrict__ WmT,
    const int* __restrict__ gid, int* __restrict__ g_start)
{
    int b = blockIdx.x;
    if (b < PRE_ZB) {
        int i = b * 256 + threadIdx.x;
        if (i < (int)ZERO_N) zbase[i] = 0;
    } else if (b < PRE_ZB + PRE_WB) {
        int i = (b - PRE_ZB) * 256 + threadIdx.x;
        if (i < 5 * 16384) {
            int m = i >> 14;
            int j = i & 16383;
            int c = j >> 7, k = j & 127;
            float w, msk;
            if (m == 0) { w = We[j]; msk = Me[j]; }
            else        { w = Wl[(m - 1) * 16384 + j]; msk = Ml[(m - 1) * 16384 + j]; }
            WmT[m * 16384 + k * 128 + c] = w * msk;
        }
    } else {
        int i = (b - PRE_ZB - PRE_WB) * 256 + threadIdx.x;
        if (i >= N_NODES) return;
        int g = gid[i];
        if (i == 0) {
            for (int x = 0; x <= g; ++x) g_start[x] = 0;
        } else {
            int gp = gid[i - 1];
            for (int x = gp + 1; x <= g; ++x) g_start[x] = i;
        }
        if (i == N_NODES - 1) {
            for (int x = g + 1; x <= N_GRAPHS; ++x) g_start[x] = N_NODES;
        }
    }
}

__global__ __launch_bounds__(256) void hist_kernel(const int* __restrict__ dst,
                                                   int* __restrict__ deg, int nE) {
    int i = blockIdx.x * 256 + threadIdx.x;
    if (i < nE) atomicAdd(&deg[dst[i]], 1);
}

// parallel scan, stage 1
__global__ __launch_bounds__(256) void scan1_kernel(const int* __restrict__ deg,
                                                    int* __restrict__ off,
                                                    int* __restrict__ bsum, int n) {
    __shared__ int s[256];
    int tid = threadIdx.x;
    int i = blockIdx.x * 256 + tid;
    int v = (i < n) ? deg[i] : 0;
    s[tid] = v;
    __syncthreads();
#pragma unroll
    for (int ofs = 1; ofs < 256; ofs <<= 1) {
        int t = (tid >= ofs) ? s[tid - ofs] : 0;
        __syncthreads();
        s[tid] += t;
        __syncthreads();
    }
    if (i < n) off[i] = s[tid] - v;
    if (tid == 255) bsum[blockIdx.x] = s[255];
}

// stage 2
__global__ __launch_bounds__(256) void scan2_kernel(int* __restrict__ bsum,
                                                    int* __restrict__ total, int nb) {
    __shared__ int s[256];
    int tid = threadIdx.x;
    int v = (tid < nb) ? bsum[tid] : 0;
    s[tid] = v;
    __syncthreads();
#pragma unroll
    for (int ofs = 1; ofs < 256; ofs <<= 1) {
        int t = (tid >= ofs) ? s[tid - ofs] : 0;
        __syncthreads();
        s[tid] += t;
        __syncthreads();
    }
    if (tid < nb) bsum[tid] = s[tid] - v;
    if (tid == 255) *total = s[255];
}

// stage 3
__global__ __launch_bounds__(256) void scan3_kernel(int* __restrict__ off,
                                                    const int* __restrict__ bsum,
                                                    const int* __restrict__ total,
                                                    int* __restrict__ pos, int n) {
    int i = blockIdx.x * 256 + threadIdx.x;
    if (i < n) {
        int o = off[i] + bsum[blockIdx.x];
        off[i] = o;
        pos[i] = o;
    }
    if (i == 0) off[n] = *total;
}

__global__ __launch_bounds__(256) void fill_kernel(const int* __restrict__ src,
                                                   const int* __restrict__ dst,
                                                   int* __restrict__ pos,
                                                   int* __restrict__ esrc, int nE) {
    int i = blockIdx.x * 256 + threadIdx.x;
    if (i < nE) {
        int p = atomicAdd(&pos[dst[i]], 1);
        esrc[p] = src[i];
    }
}

// agg[n][:] = sum over incoming edges of H[src][:]
// 2 nodes/wave (float4 x 32 lanes), edge loop unrolled x8 (16 row-streams/wave)
__global__ __launch_bounds__(256) void aggregate_kernel(const float* __restrict__ H,
                                                        const int* __restrict__ off,
                                                        const int* __restrict__ esrc,
                                                        float* __restrict__ agg, int nN) {
    int wid  = (blockIdx.x * 256 + threadIdx.x) >> 6;
    int lane = threadIdx.x & 63;
    int half = lane >> 5;
    int l4   = lane & 31;
    int node = wid * 2 + half;
    if (node >= nN) return;
    int beg = off[node], end = off[node + 1];
    const float4* H4 = (const float4*)H;
    float4 a0 = make_float4(0.f, 0.f, 0.f, 0.f);
    float4 a1 = make_float4(0.f, 0.f, 0.f, 0.f);
    float4 a2 = make_float4(0.f, 0.f, 0.f, 0.f);
    float4 a3 = make_float4(0.f, 0.f, 0.f, 0.f);
    int e = beg;
    for (; e + 7 < end; e += 8) {
        int s0 = esrc[e],     s1 = esrc[e + 1], s2 = esrc[e + 2], s3 = esrc[e + 3];
        int s4 = esrc[e + 4], s5 = esrc[e + 5], s6 = esrc[e + 6], s7 = esrc[e + 7];
        float4 v0 = H4[(size_t)s0 * 32 + l4];
        float4 v1 = H4[(size_t)s1 * 32 + l4];
        float4 v2 = H4[(size_t)s2 * 32 + l4];
        float4 v3 = H4[(size_t)s3 * 32 + l4];
        float4 v4 = H4[(size_t)s4 * 32 + l4];
        float4 v5 = H4[(size_t)s5 * 32 + l4];
        float4 v6 = H4[(size_t)s6 * 32 + l4];
        float4 v7 = H4[(size_t)s7 * 32 + l4];
        a0.x += v0.x; a0.y += v0.y; a0.z += v0.z; a0.w += v0.w;
        a1.x += v1.x; a1.y += v1.y; a1.z += v1.z; a1.w += v1.w;
        a2.x += v2.x; a2.y += v2.y; a2.z += v2.z; a2.w += v2.w;
        a3.x += v3.x; a3.y += v3.y; a3.z += v3.z; a3.w += v3.w;
        a0.x += v4.x; a0.y += v4.y; a0.z += v4.z; a0.w += v4.w;
        a1.x += v5.x; a1.y += v5.y; a1.z += v5.z; a1.w += v5.w;
        a2.x += v6.x; a2.y += v6.y; a2.z += v6.z; a2.w += v6.w;
        a3.x += v7.x; a3.y += v7.y; a3.z += v7.z; a3.w += v7.w;
    }
    for (; e + 3 < end; e += 4) {
        int s0 = esrc[e], s1 = esrc[e + 1], s2 = esrc[e + 2], s3 = esrc[e + 3];
        float4 v0 = H4[(size_t)s0 * 32 + l4];
        float4 v1 = H4[(size_t)s1 * 32 + l4];
        float4 v2 = H4[(size_t)s2 * 32 + l4];
        float4 v3 = H4[(size_t)s3 * 32 + l4];
        a0.x += v0.x; a0.y += v0.y; a0.z += v0.z; a0.w += v0.w;
        a1.x += v1.x; a1.y += v1.y; a1.z += v1.z; a1.w += v1.w;
        a2.x += v2.x; a2.y += v2.y; a2.z += v2.z; a2.w += v2.w;
        a3.x += v3.x; a3.y += v3.y; a3.z += v3.z; a3.w += v3.w;
    }
    for (; e < end; ++e) {
        float4 v0 = H4[(size_t)esrc[e] * 32 + l4];
        a0.x += v0.x; a0.y += v0.y; a0.z += v0.z; a0.w += v0.w;
    }
    a0.x += a1.x; a0.y += a1.y; a0.z += a1.z; a0.w += a1.w;
    a2.x += a3.x; a2.y += a3.y; a2.z += a3.z; a2.w += a3.w;
    a0.x += a2.x; a0.y += a2.y; a0.z += a2.z; a0.w += a2.w;
    ((float4*)agg)[(size_t)node * 32 + l4] = a0;
}

// GEMM v5: 256 threads (4 waves), 64 rows x 128 cols per block, grid 782
// (12.2 waves/CU). Per thread: 4 interleaved rows (r = ty + 16i) x 8 cols;
// A read as ds_read_b128 over 4 k's. T14 async-stage: issue chunk c+1 global
// loads into regs before computing chunk c; ds_write after the barrier.
// Single-buffered LDS (25.6 KB).
__global__ __launch_bounds__(256) void gemm_kernel(
    const float* __restrict__ A, const float* __restrict__ WmT,
    const float* __restrict__ bias, const float* __restrict__ snorm,
    float* __restrict__ Z, float* __restrict__ colsum, int nRows)
{
    __shared__ float4 As4[TILE_R * 9];        // [64][9] f4 (8 data + 1 pad) = 9216 B
    __shared__ float  Ws[KC][128];            // 16384 B
    int tid = threadIdx.x;
    int tx = tid & 15;                        // 16 col groups (cols c0 and 64+c0)
    int ty = tid >> 4;                        // 16 row groups
    int r0 = blockIdx.x * TILE_R;
    const float4* A4 = (const float4*)A;
    const float4* W4 = (const float4*)WmT;
    float4* WsD = (float4*)&Ws[0][0];

    // staging registers (T14: global->reg early, reg->LDS late)
    float4 wreg[4];
    float4 areg[2];
    int ar[2], ag[2];
#pragma unroll
    for (int it = 0; it < 2; ++it) {
        int e = tid + it * 256;
        ar[it] = e >> 3;
        ag[it] = e & 7;
    }

    // prologue: load chunk 0, write LDS, barrier
#pragma unroll
    for (int it = 0; it < 4; ++it) wreg[it] = W4[tid + it * 256];
#pragma unroll
    for (int it = 0; it < 2; ++it) {
        int gr = r0 + ar[it];
        if (gr >= nRows) gr = nRows - 1;
        areg[it] = A4[(size_t)gr * 32 + ag[it]];
    }
#pragma unroll
    for (int it = 0; it < 4; ++it) WsD[tid + it * 256] = wreg[it];
#pragma unroll
    for (int it = 0; it < 2; ++it) As4[ar[it] * 9 + ag[it]] = areg[it];
    __syncthreads();

    float acc[4][8];
#pragma unroll
    for (int i = 0; i < 4; ++i)
#pragma unroll
        for (int j = 0; j < 8; ++j) acc[i][j] = 0.f;

    for (int c = 0; c < 4; ++c) {
        if (c < 3) {   // issue next chunk's loads (latency hides under compute)
#pragma unroll
            for (int it = 0; it < 4; ++it)
                wreg[it] = W4[(c + 1) * 1024 + tid + it * 256];
#pragma unroll
            for (int it = 0; it < 2; ++it) {
                int gr = r0 + ar[it];
                if (gr >= nRows) gr = nRows - 1;
                areg[it] = A4[(size_t)gr * 32 + (c + 1) * 8 + ag[it]];
            }
        }
        // compute current chunk from LDS
#pragma unroll
        for (int q = 0; q < 8; ++q) {
            float4 av[4];
#pragma unroll
            for (int i = 0; i < 4; ++i)
                av[i] = As4[(ty + 16 * i) * 9 + q];   // interleaved rows, 2-way max
            const float* avf = (const float*)av;
#pragma unroll
            for (int j = 0; j < 4; ++j) {
                float4 w0 = *(const float4*)&Ws[q * 4 + j][tx * 4];
                float4 w1 = *(const float4*)&Ws[q * 4 + j][64 + tx * 4];
#pragma unroll
                for (int i = 0; i < 4; ++i) {
                    float a = avf[i * 4 + j];
                    acc[i][0] += a * w0.x; acc[i][1] += a * w0.y;
                    acc[i][2] += a * w0.z; acc[i][3] += a * w0.w;
                    acc[i][4] += a * w1.x; acc[i][5] += a * w1.y;
                    acc[i][6] += a * w1.z; acc[i][7] += a * w1.w;
                }
            }
        }
        __syncthreads();                      // LDS reads done (also drains vmcnt)
        if (c < 3) {
#pragma unroll
            for (int it = 0; it < 4; ++it) WsD[tid + it * 256] = wreg[it];
#pragma unroll
            for (int it = 0; it < 2; ++it) As4[ar[it] * 9 + ag[it]] = areg[it];
        }
        __syncthreads();                      // writes visible
    }

    // ---- epilogue ----
    int c0 = tx * 4;
    float bl[8];
#pragma unroll
    for (int j = 0; j < 4; ++j) {
        bl[j]     = bias[c0 + j];
        bl[4 + j] = bias[64 + c0 + j];
    }
    float cs[8], cq[8];
#pragma unroll
    for (int j = 0; j < 8; ++j) { cs[j] = 0.f; cq[j] = 0.f; }

#pragma unroll
    for (int i = 0; i < 4; ++i) {
        int r = r0 + ty + 16 * i;
        if (r < nRows) {
            float sn = snorm ? snorm[r] : 1.0f;
            float4 o0, o1;
            float v;
            v = (acc[i][0] + bl[0]) * sn; o0.x = v; cs[0] += v; cq[0] += v * v;
            v = (acc[i][1] + bl[1]) * sn; o0.y = v; cs[1] += v; cq[1] += v * v;
            v = (acc[i][2] + bl[2]) * sn; o0.z = v; cs[2] += v; cq[2] += v * v;
            v = (acc[i][3] + bl[3]) * sn; o0.w = v; cs[3] += v; cq[3] += v * v;
            v = (acc[i][4] + bl[4]) * sn; o1.x = v; cs[4] += v; cq[4] += v * v;
            v = (acc[i][5] + bl[5]) * sn; o1.y = v; cs[5] += v; cq[5] += v * v;
            v = (acc[i][6] + bl[6]) * sn; o1.z = v; cs[6] += v; cq[6] += v * v;
            v = (acc[i][7] + bl[7]) * sn; o1.w = v; cs[7] += v; cq[7] += v * v;
            *(float4*)(Z + (size_t)r * 128 + c0)      = o0;
            *(float4*)(Z + (size_t)r * 128 + 64 + c0) = o1;
        }
    }

    if (colsum) {
        float* red = &Ws[0][0];               // 16*128 floats = 8 KB, fits in Ws
        for (int round = 0; round < 2; ++round) {
            float* srcp = round ? cq : cs;
#pragma unroll
            for (int j = 0; j < 4; ++j) {
                red[ty * 128 + c0 + j]      = srcp[j];
                red[ty * 128 + 64 + c0 + j] = srcp[4 + j];
            }
            __syncthreads();
            if (tid < 128) {
                float s = 0.f;
#pragma unroll
                for (int t = 0; t < 16; ++t) s += red[t * 128 + tid];
                atomicAdd(&colsum[round * 128 + tid], s);
            }
            __syncthreads();
        }
    }
}

// H += relu((Z - mu)*rsqrt(var+eps)*gamma + beta); BN params inline from csum
__global__ __launch_bounds__(256) void apply_kernel(const float* __restrict__ Z,
                                                    const float* __restrict__ csum,
                                                    const float* __restrict__ gamma,
                                                    const float* __restrict__ beta,
                                                    float* __restrict__ H, int n4, int layer) {
    int i = blockIdx.x * 256 + threadIdx.x;
    if (i >= n4) return;
    int c4 = i & 31;
    const float invN = 1.0f / (float)N_NODES;
    float4 s  = ((const float4*)(csum  + layer * 256))[c4];
    float4 q  = ((const float4*)(csum  + layer * 256 + 128))[c4];
    float4 g  = ((const float4*)(gamma + layer * 128))[c4];
    float4 be = ((const float4*)(beta  + layer * 128))[c4];
    float4 z = ((const float4*)Z)[i];
    float4 h = ((float4*)H)[i];
    float mu, var, sc, sh;
    mu = s.x * invN; var = q.x * invN - mu * mu; sc = g.x * rsqrtf(var + BN_EPS); sh = be.x - mu * sc;
    h.x += fmaxf(z.x * sc + sh, 0.f);
    mu = s.y * invN; var = q.y * invN - mu * mu; sc = g.y * rsqrtf(var + BN_EPS); sh = be.y - mu * sc;
    h.y += fmaxf(z.y * sc + sh, 0.f);
    mu = s.z * invN; var = q.z * invN - mu * mu; sc = g.z * rsqrtf(var + BN_EPS); sh = be.z - mu * sc;
    h.z += fmaxf(z.z * sc + sh, 0.f);
    mu = s.w * invN; var = q.w * invN - mu * mu; sc = g.w * rsqrtf(var + BN_EPS); sh = be.w - mu * sc;
    h.w += fmaxf(z.w * sc + sh, 0.f);
    ((float4*)H)[i] = h;
}

// dense per-graph reduction using sorted-gid boundaries
__global__ __launch_bounds__(256) void readout2_kernel(const float* __restrict__ H,
                                                       const int* __restrict__ g_start,
                                                       float* __restrict__ sums) {
    int g     = blockIdx.x / RSPLIT;
    int chunk = blockIdx.x % RSPLIT;
    int beg = g_start[g], end = g_start[g + 1];
    int col  = threadIdx.x & 127;
    int half = threadIdx.x >> 7;
    float acc = 0.f;
    for (int r = beg + chunk * 2 + half; r < end; r += RSPLIT * 2) {
        acc += H[(size_t)r * 128 + col];
    }
    if (acc != 0.f || half == 0)
        atomicAdd(&sums[g * 128 + col], acc);
}

__global__ __launch_bounds__(128) void final_kernel(const float* __restrict__ sums,
                                                    const int* __restrict__ g_start,
                                                    const float* __restrict__ roW,
                                                    const float* __restrict__ rob,
                                                    float* __restrict__ out) {
    __shared__ float row[128];
    int g = blockIdx.x;
    int t = threadIdx.x;
    float c = fmaxf((float)(g_start[g + 1] - g_start[g]), 1.0f);
    row[t] = sums[g * 128 + t] / c;
    __syncthreads();
    if (t < N_CLASSES) {
        float s = rob[t];
        for (int k = 0; k < 128; ++k) s += row[k] * roW[t * 128 + k];
        out[g * N_CLASSES + t] = s;
    }
}

extern "C" void kernel_launch(void* const* d_in, const int* in_sizes, int n_in,
                              void* d_out, int out_size, void* d_ws, size_t ws_size,
                              hipStream_t stream) {
    const float* h0      = (const float*)d_in[0];
    const float* snorm   = (const float*)d_in[1];
    const int*   src     = (const int*)d_in[2];
    const int*   dst     = (const int*)d_in[3];
    const int*   gid     = (const int*)d_in[4];
    const float* embedW  = (const float*)d_in[5];
    const float* embedM  = (const float*)d_in[6];
    const float* embedB  = (const float*)d_in[7];
    const float* layerW  = (const float*)d_in[8];
    const float* layerM  = (const float*)d_in[9];
    const float* layerB  = (const float*)d_in[10];
    const float* gamma   = (const float*)d_in[11];
    const float* beta    = (const float*)d_in[12];
    const float* roW     = (const float*)d_in[13];
    const float* rob     = (const float*)d_in[14];
    float* out = (float*)d_out;

    float* ws   = (float*)d_ws;
    float* wmT  = ws + OFF_WMT;
    float* H    = ws + OFF_H;
    float* Z    = ws + OFF_Z;
    float* AGG  = ws + OFF_AGG;
    float* csum = ws + OFF_CSUM;
    float* sums = ws + OFF_SUMS;
    int*   deg  = (int*)(ws + OFF_DEG);
    int*   offs = (int*)(ws + OFF_OFFS);
    int*   pos  = (int*)(ws + OFF_POS);
    int*   esrc = (int*)(ws + OFF_ESRC);
    int*   gst  = (int*)(ws + OFF_GST);
    int*   bsum = (int*)(ws + OFF_BSUM);
    int*   tot  = (int*)(ws + OFF_TOT);

    // fused preamble: zero | wmask | bounds
    preamble_kernel<<<PRE_ZB + PRE_WB + PRE_BB, 256, 0, stream>>>(
        (int*)(ws + OFF_ZERO), embedW, embedM, layerW, layerM, wmT, gid, gst);
    // CSR build (once per call, reused by all 4 layers)
    hist_kernel<<<(N_EDGES + 255) / 256, 256, 0, stream>>>(dst, deg, N_EDGES);
    scan1_kernel<<<SCAN_B, 256, 0, stream>>>(deg, offs, bsum, N_NODES);
    scan2_kernel<<<1, 256, 0, stream>>>(bsum, tot, SCAN_B);
    scan3_kernel<<<SCAN_B, 256, 0, stream>>>(offs, bsum, tot, pos, N_NODES);
    fill_kernel<<<(N_EDGES + 255) / 256, 256, 0, stream>>>(src, dst, pos, esrc, N_EDGES);

    // embedding: H = h0 @ (embed_W*mask)^T + embed_b
    gemm_kernel<<<GEMM_GRID, 256, 0, stream>>>(h0, wmT, embedB, nullptr, H, nullptr, N_NODES);

    const int agg_grid = (N_NODES / 2 + 3) / 4;   // 2 nodes/wave, 4 waves/block
    for (int l = 0; l < N_LAYERS; ++l) {
        aggregate_kernel<<<agg_grid, 256, 0, stream>>>(H, offs, esrc, AGG, N_NODES);
        gemm_kernel<<<GEMM_GRID, 256, 0, stream>>>(AGG, wmT + (1 + l) * 16384,
                                                   layerB + l * 128, snorm,
                                                   Z, csum + l * 256, N_NODES);
        apply_kernel<<<(N_NODES * HID / 4) / 256, 256, 0, stream>>>(
            Z, csum, gamma, beta, H, N_NODES * HID / 4, l);
    }

    readout2_kernel<<<N_GRAPHS * RSPLIT, 256, 0, stream>>>(H, gst, sums);
    final_kernel<<<N_GRAPHS, 128, 0, stream>>>(sums, gst, roW, rob, out);
}

// Round 10
// 593.085 us; speedup vs baseline: 1.2784x; 1.2784x over previous
//
#include <hip/hip_runtime.h>
#include <hip/hip_bf16.h>

#define N_NODES   50000
#define N_EDGES   600000
#define HID       128
#define N_LAYERS  4
#define N_GRAPHS  128
#define N_CLASSES 10
#define BN_EPS    1e-5f

#define TILE_R 64           // 8 ty-groups x 8 interleaved rows (r = ty + 8i)
#define KC     32
#define RSPLIT 8
#define SCAN_B 196          // ceil(50000/256)
#define GEMM_GRID ((N_NODES + TILE_R - 1) / TILE_R)   // 782

// ---------------- workspace layout (in 4-byte elements) ----------------
#define OFF_WMT   0u                         // 5 * 16384 masked+transposed weights [k][c]
#define OFF_H     81920u                     // 50000*128 fp32
#define OFF_Z     (OFF_H   + 6400000u)
#define OFF_AGG   (OFF_Z   + 6400000u)       // aggregate output [50000][128]
#define OFF_ZERO  (OFF_AGG + 6400000u)       // start of zero-initialized region
#define OFF_CSUM  OFF_ZERO                   // [4][2][128] = 1024 f
#define OFF_SUMS  (OFF_CSUM + 1024u)         // [128][128]  = 16384 f
#define OFF_DEG   (OFF_SUMS + 16384u)        // [50000] int
#define ZERO_N    (1024u + 16384u + 50000u)  // 67408 elements
#define OFF_OFFS  (OFF_ZERO + ZERO_N)        // [50001] int (padded to 50004)
#define OFF_POS   (OFF_OFFS + 50004u)        // [50000] int
#define OFF_ESRC  (OFF_POS  + 50000u)        // [600000] int
#define OFF_GST   (OFF_ESRC + 600000u)       // [129] int graph boundaries (pad 132)
#define OFF_BSUM  (OFF_GST  + 132u)          // [196] int block sums
#define OFF_TOT   (OFF_BSUM + 196u)          // [1] int total
#define OFF_HBF   (OFF_TOT  + 4u)            // [50000][128] bf16 = 3.2M u32

// preamble block ranges
#define PRE_ZB 264
#define PRE_WB 320
#define PRE_BB 196

// bf16 helpers (RNE)
__device__ __forceinline__ unsigned int bf16_of(float f) {
    unsigned int u = __float_as_uint(f);
    return (u + 0x7fffu + ((u >> 16) & 1u)) >> 16;
}
__device__ __forceinline__ unsigned int pack_bf2(float lo, float hi) {
    return bf16_of(lo) | (bf16_of(hi) << 16);
}

// fused preamble: zero workspace region | masked+transposed weights | graph bounds
__global__ __launch_bounds__(256) void preamble_kernel(
    int* __restrict__ zbase,
    const float* __restrict__ We, const float* __restrict__ Me,
    const float* __restrict__ Wl, const float* __restrict__ Ml,
    float* __restrict__ WmT,
    const int* __restrict__ gid, int* __restrict__ g_start)
{
    int b = blockIdx.x;
    if (b < PRE_ZB) {
        int i = b * 256 + threadIdx.x;
        if (i < (int)ZERO_N) zbase[i] = 0;
    } else if (b < PRE_ZB + PRE_WB) {
        int i = (b - PRE_ZB) * 256 + threadIdx.x;
        if (i < 5 * 16384) {
            int m = i >> 14;
            int j = i & 16383;
            int c = j >> 7, k = j & 127;
            float w, msk;
            if (m == 0) { w = We[j]; msk = Me[j]; }
            else        { w = Wl[(m - 1) * 16384 + j]; msk = Ml[(m - 1) * 16384 + j]; }
            WmT[m * 16384 + k * 128 + c] = w * msk;
        }
    } else {
        int i = (b - PRE_ZB - PRE_WB) * 256 + threadIdx.x;
        if (i >= N_NODES) return;
        int g = gid[i];
        if (i == 0) {
            for (int x = 0; x <= g; ++x) g_start[x] = 0;
        } else {
            int gp = gid[i - 1];
            for (int x = gp + 1; x <= g; ++x) g_start[x] = i;
        }
        if (i == N_NODES - 1) {
            for (int x = g + 1; x <= N_GRAPHS; ++x) g_start[x] = N_NODES;
        }
    }
}

__global__ __launch_bounds__(256) void hist_kernel(const int* __restrict__ dst,
                                                   int* __restrict__ deg, int nE) {
    int i = blockIdx.x * 256 + threadIdx.x;
    if (i < nE) atomicAdd(&deg[dst[i]], 1);
}

__global__ __launch_bounds__(256) void scan1_kernel(const int* __restrict__ deg,
                                                    int* __restrict__ off,
                                                    int* __restrict__ bsum, int n) {
    __shared__ int s[256];
    int tid = threadIdx.x;
    int i = blockIdx.x * 256 + tid;
    int v = (i < n) ? deg[i] : 0;
    s[tid] = v;
    __syncthreads();
#pragma unroll
    for (int ofs = 1; ofs < 256; ofs <<= 1) {
        int t = (tid >= ofs) ? s[tid - ofs] : 0;
        __syncthreads();
        s[tid] += t;
        __syncthreads();
    }
    if (i < n) off[i] = s[tid] - v;
    if (tid == 255) bsum[blockIdx.x] = s[255];
}

__global__ __launch_bounds__(256) void scan2_kernel(int* __restrict__ bsum,
                                                    int* __restrict__ total, int nb) {
    __shared__ int s[256];
    int tid = threadIdx.x;
    int v = (tid < nb) ? bsum[tid] : 0;
    s[tid] = v;
    __syncthreads();
#pragma unroll
    for (int ofs = 1; ofs < 256; ofs <<= 1) {
        int t = (tid >= ofs) ? s[tid - ofs] : 0;
        __syncthreads();
        s[tid] += t;
        __syncthreads();
    }
    if (tid < nb) bsum[tid] = s[tid] - v;
    if (tid == 255) *total = s[255];
}

__global__ __launch_bounds__(256) void scan3_kernel(int* __restrict__ off,
                                                    const int* __restrict__ bsum,
                                                    const int* __restrict__ total,
                                                    int* __restrict__ pos, int n) {
    int i = blockIdx.x * 256 + threadIdx.x;
    if (i < n) {
        int o = off[i] + bsum[blockIdx.x];
        off[i] = o;
        pos[i] = o;
    }
    if (i == 0) off[n] = *total;
}

__global__ __launch_bounds__(256) void fill_kernel(const int* __restrict__ src,
                                                   const int* __restrict__ dst,
                                                   int* __restrict__ pos,
                                                   int* __restrict__ esrc, int nE) {
    int i = blockIdx.x * 256 + threadIdx.x;
    if (i < nE) {
        int p = atomicAdd(&pos[dst[i]], 1);
        esrc[p] = src[i];
    }
}

// agg[n][:] = sum over incoming edges of Hbf[src][:]  (bf16 rows, fp32 accumulate)
// 2 nodes/wave (uint2 x 32 lanes = 256B/row), edge loop unrolled x8
__global__ __launch_bounds__(256) void aggregate_kernel(const unsigned int* __restrict__ Hbf,
                                                        const int* __restrict__ off,
                                                        const int* __restrict__ esrc,
                                                        float* __restrict__ agg, int nN) {
    int wid  = (blockIdx.x * 256 + threadIdx.x) >> 6;
    int lane = threadIdx.x & 63;
    int half = lane >> 5;
    int l4   = lane & 31;
    int node = wid * 2 + half;
    if (node >= nN) return;
    int beg = off[node], end = off[node + 1];
    const uint2* H2 = (const uint2*)Hbf;      // 32 uint2 per row (4 bf16 each)
    float4 a0 = make_float4(0.f, 0.f, 0.f, 0.f);
    float4 a1 = make_float4(0.f, 0.f, 0.f, 0.f);
    float4 a2 = make_float4(0.f, 0.f, 0.f, 0.f);
    float4 a3 = make_float4(0.f, 0.f, 0.f, 0.f);
#define ACCUM(AX, V)                                                        \
    AX.x += __uint_as_float((V).x << 16);                                   \
    AX.y += __uint_as_float((V).x & 0xffff0000u);                           \
    AX.z += __uint_as_float((V).y << 16);                                   \
    AX.w += __uint_as_float((V).y & 0xffff0000u);
    int e = beg;
    for (; e + 7 < end; e += 8) {
        int s0 = esrc[e],     s1 = esrc[e + 1], s2 = esrc[e + 2], s3 = esrc[e + 3];
        int s4 = esrc[e + 4], s5 = esrc[e + 5], s6 = esrc[e + 6], s7 = esrc[e + 7];
        uint2 v0 = H2[(size_t)s0 * 32 + l4];
        uint2 v1 = H2[(size_t)s1 * 32 + l4];
        uint2 v2 = H2[(size_t)s2 * 32 + l4];
        uint2 v3 = H2[(size_t)s3 * 32 + l4];
        uint2 v4 = H2[(size_t)s4 * 32 + l4];
        uint2 v5 = H2[(size_t)s5 * 32 + l4];
        uint2 v6 = H2[(size_t)s6 * 32 + l4];
        uint2 v7 = H2[(size_t)s7 * 32 + l4];
        ACCUM(a0, v0) ACCUM(a1, v1) ACCUM(a2, v2) ACCUM(a3, v3)
        ACCUM(a0, v4) ACCUM(a1, v5) ACCUM(a2, v6) ACCUM(a3, v7)
    }
    for (; e + 3 < end; e += 4) {
        int s0 = esrc[e], s1 = esrc[e + 1], s2 = esrc[e + 2], s3 = esrc[e + 3];
        uint2 v0 = H2[(size_t)s0 * 32 + l4];
        uint2 v1 = H2[(size_t)s1 * 32 + l4];
        uint2 v2 = H2[(size_t)s2 * 32 + l4];
        uint2 v3 = H2[(size_t)s3 * 32 + l4];
        ACCUM(a0, v0) ACCUM(a1, v1) ACCUM(a2, v2) ACCUM(a3, v3)
    }
    for (; e < end; ++e) {
        uint2 v0 = H2[(size_t)esrc[e] * 32 + l4];
        ACCUM(a0, v0)
    }
#undef ACCUM
    a0.x += a1.x; a0.y += a1.y; a0.z += a1.z; a0.w += a1.w;
    a2.x += a3.x; a2.y += a3.y; a2.z += a3.z; a2.w += a3.w;
    a0.x += a2.x; a0.y += a2.y; a0.z += a2.z; a0.w += a2.w;
    // agg row: lane l4 holds cols [l4*4 .. l4*4+3]  (4 bf16 unpacked in order)
    ((float4*)agg)[(size_t)node * 32 + l4] = a0;
}

// GEMM (R8-proven): 128 threads, 64 rows x 128 cols, 8 interleaved rows/thread.
// Optional hbf: also emit bf16 copy of output rows (embedding call).
__global__ __launch_bounds__(128) void gemm_kernel(
    const float* __restrict__ A, const float* __restrict__ WmT,
    const float* __restrict__ bias, const float* __restrict__ snorm,
    float* __restrict__ Z, float* __restrict__ colsum,
    unsigned int* __restrict__ hbf, int nRows)
{
    __shared__ float4 As4[TILE_R * 9];        // [64][9] f4 rows (8 data + 1 pad)
    __shared__ float  Ws[KC][128];
    int tid = threadIdx.x;
    int tx = tid & 15;
    int ty = tid >> 4;                        // 8 row groups
    int r0 = blockIdx.x * TILE_R;
    const float4* A4 = (const float4*)A;

    float acc[8][8];
#pragma unroll
    for (int i = 0; i < 8; ++i)
#pragma unroll
        for (int j = 0; j < 8; ++j) acc[i][j] = 0.f;

    for (int c = 0; c < 4; ++c) {
        if (c) __syncthreads();
        {
            const float4* W4 = (const float4*)(WmT + c * KC * 128);
            float4* Wd = (float4*)&Ws[0][0];
#pragma unroll
            for (int it = 0; it < 8; ++it) Wd[tid + it * 128] = W4[tid + it * 128];
        }
        {
#pragma unroll
            for (int it = 0; it < 4; ++it) {
                int e = tid + it * 128;
                int r = e >> 3, g = e & 7;
                int gr = r0 + r;
                if (gr >= nRows) gr = nRows - 1;
                As4[r * 9 + g] = A4[(size_t)gr * 32 + c * 8 + g];
            }
        }
        __syncthreads();
#pragma unroll
        for (int q = 0; q < 8; ++q) {
            float4 av[8];
#pragma unroll
            for (int i = 0; i < 8; ++i)
                av[i] = As4[(ty + 8 * i) * 9 + q];
            const float* avf = (const float*)av;
#pragma unroll
            for (int j = 0; j < 4; ++j) {
                float4 w0 = *(const float4*)&Ws[q * 4 + j][tx * 4];
                float4 w1 = *(const float4*)&Ws[q * 4 + j][64 + tx * 4];
#pragma unroll
                for (int i = 0; i < 8; ++i) {
                    float a = avf[i * 4 + j];
                    acc[i][0] += a * w0.x; acc[i][1] += a * w0.y;
                    acc[i][2] += a * w0.z; acc[i][3] += a * w0.w;
                    acc[i][4] += a * w1.x; acc[i][5] += a * w1.y;
                    acc[i][6] += a * w1.z; acc[i][7] += a * w1.w;
                }
            }
        }
    }
    __syncthreads();

    int c0 = tx * 4;
    float bl[8];
#pragma unroll
    for (int j = 0; j < 4; ++j) {
        bl[j]     = bias[c0 + j];
        bl[4 + j] = bias[64 + c0 + j];
    }
    float cs[8], cq[8];
#pragma unroll
    for (int j = 0; j < 8; ++j) { cs[j] = 0.f; cq[j] = 0.f; }

#pragma unroll
    for (int i = 0; i < 8; ++i) {
        int r = r0 + ty + 8 * i;
        if (r < nRows) {
            float sn = snorm ? snorm[r] : 1.0f;
            float4 o0, o1;
            float v;
            v = (acc[i][0] + bl[0]) * sn; o0.x = v; cs[0] += v; cq[0] += v * v;
            v = (acc[i][1] + bl[1]) * sn; o0.y = v; cs[1] += v; cq[1] += v * v;
            v = (acc[i][2] + bl[2]) * sn; o0.z = v; cs[2] += v; cq[2] += v * v;
            v = (acc[i][3] + bl[3]) * sn; o0.w = v; cs[3] += v; cq[3] += v * v;
            v = (acc[i][4] + bl[4]) * sn; o1.x = v; cs[4] += v; cq[4] += v * v;
            v = (acc[i][5] + bl[5]) * sn; o1.y = v; cs[5] += v; cq[5] += v * v;
            v = (acc[i][6] + bl[6]) * sn; o1.z = v; cs[6] += v; cq[6] += v * v;
            v = (acc[i][7] + bl[7]) * sn; o1.w = v; cs[7] += v; cq[7] += v * v;
            *(float4*)(Z + (size_t)r * 128 + c0)      = o0;
            *(float4*)(Z + (size_t)r * 128 + 64 + c0) = o1;
            if (hbf) {
                hbf[(size_t)r * 64 + tx * 2]      = pack_bf2(o0.x, o0.y);
                hbf[(size_t)r * 64 + tx * 2 + 1]  = pack_bf2(o0.z, o0.w);
                hbf[(size_t)r * 64 + 32 + tx * 2]     = pack_bf2(o1.x, o1.y);
                hbf[(size_t)r * 64 + 32 + tx * 2 + 1] = pack_bf2(o1.z, o1.w);
            }
        }
    }

    if (colsum) {
        float* red = &Ws[0][0];
        for (int round = 0; round < 2; ++round) {
            float* srcp = round ? cq : cs;
#pragma unroll
            for (int j = 0; j < 4; ++j) {
                red[ty * 128 + c0 + j]      = srcp[j];
                red[ty * 128 + 64 + c0 + j] = srcp[4 + j];
            }
            __syncthreads();
            {
                float s = 0.f;
#pragma unroll
                for (int t = 0; t < 8; ++t) s += red[t * 128 + tid];
                atomicAdd(&colsum[round * 128 + tid], s);
            }
            __syncthreads();
        }
    }
}

// H += relu(BN(Z)); also emit bf16 H copy for the next layer's gather
__global__ __launch_bounds__(256) void apply_kernel(const float* __restrict__ Z,
                                                    const float* __restrict__ csum,
                                                    const float* __restrict__ gamma,
                                                    const float* __restrict__ beta,
                                                    float* __restrict__ H,
                                                    unsigned int* __restrict__ hbf,
                                                    int n4, int layer) {
    int i = blockIdx.x * 256 + threadIdx.x;
    if (i >= n4) return;
    int c4 = i & 31;
    const float invN = 1.0f / (float)N_NODES;
    float4 s  = ((const float4*)(csum  + layer * 256))[c4];
    float4 q  = ((const float4*)(csum  + layer * 256 + 128))[c4];
    float4 g  = ((const float4*)(gamma + layer * 128))[c4];
    float4 be = ((const float4*)(beta  + layer * 128))[c4];
    float4 z = ((const float4*)Z)[i];
    float4 h = ((float4*)H)[i];
    float mu, var, sc, sh;
    mu = s.x * invN; var = q.x * invN - mu * mu; sc = g.x * rsqrtf(var + BN_EPS); sh = be.x - mu * sc;
    h.x += fmaxf(z.x * sc + sh, 0.f);
    mu = s.y * invN; var = q.y * invN - mu * mu; sc = g.y * rsqrtf(var + BN_EPS); sh = be.y - mu * sc;
    h.y += fmaxf(z.y * sc + sh, 0.f);
    mu = s.z * invN; var = q.z * invN - mu * mu; sc = g.z * rsqrtf(var + BN_EPS); sh = be.z - mu * sc;
    h.z += fmaxf(z.z * sc + sh, 0.f);
    mu = s.w * invN; var = q.w * invN - mu * mu; sc = g.w * rsqrtf(var + BN_EPS); sh = be.w - mu * sc;
    h.w += fmaxf(z.w * sc + sh, 0.f);
    ((float4*)H)[i] = h;
    hbf[i * 2]     = pack_bf2(h.x, h.y);
    hbf[i * 2 + 1] = pack_bf2(h.z, h.w);
}

// dense per-graph reduction using sorted-gid boundaries (fp32 H)
__global__ __launch_bounds__(256) void readout2_kernel(const float* __restrict__ H,
                                                       const int* __restrict__ g_start,
                                                       float* __restrict__ sums) {
    int g     = blockIdx.x / RSPLIT;
    int chunk = blockIdx.x % RSPLIT;
    int beg = g_start[g], end = g_start[g + 1];
    int col  = threadIdx.x & 127;
    int half = threadIdx.x >> 7;
    float acc = 0.f;
    for (int r = beg + chunk * 2 + half; r < end; r += RSPLIT * 2) {
        acc += H[(size_t)r * 128 + col];
    }
    if (acc != 0.f || half == 0)
        atomicAdd(&sums[g * 128 + col], acc);
}

__global__ __launch_bounds__(128) void final_kernel(const float* __restrict__ sums,
                                                    const int* __restrict__ g_start,
                                                    const float* __restrict__ roW,
                                                    const float* __restrict__ rob,
                                                    float* __restrict__ out) {
    __shared__ float row[128];
    int g = blockIdx.x;
    int t = threadIdx.x;
    float c = fmaxf((float)(g_start[g + 1] - g_start[g]), 1.0f);
    row[t] = sums[g * 128 + t] / c;
    __syncthreads();
    if (t < N_CLASSES) {
        float s = rob[t];
        for (int k = 0; k < 128; ++k) s += row[k] * roW[t * 128 + k];
        out[g * N_CLASSES + t] = s;
    }
}

extern "C" void kernel_launch(void* const* d_in, const int* in_sizes, int n_in,
                              void* d_out, int out_size, void* d_ws, size_t ws_size,
                              hipStream_t stream) {
    const float* h0      = (const float*)d_in[0];
    const float* snorm   = (const float*)d_in[1];
    const int*   src     = (const int*)d_in[2];
    const int*   dst     = (const int*)d_in[3];
    const int*   gid     = (const int*)d_in[4];
    const float* embedW  = (const float*)d_in[5];
    const float* embedM  = (const float*)d_in[6];
    const float* embedB  = (const float*)d_in[7];
    const float* layerW  = (const float*)d_in[8];
    const float* layerM  = (const float*)d_in[9];
    const float* layerB  = (const float*)d_in[10];
    const float* gamma   = (const float*)d_in[11];
    const float* beta    = (const float*)d_in[12];
    const float* roW     = (const float*)d_in[13];
    const float* rob     = (const float*)d_in[14];
    float* out = (float*)d_out;

    float* ws   = (float*)d_ws;
    float* wmT  = ws + OFF_WMT;
    float* H    = ws + OFF_H;
    float* Z    = ws + OFF_Z;
    float* AGG  = ws + OFF_AGG;
    float* csum = ws + OFF_CSUM;
    float* sums = ws + OFF_SUMS;
    int*   deg  = (int*)(ws + OFF_DEG);
    int*   offs = (int*)(ws + OFF_OFFS);
    int*   pos  = (int*)(ws + OFF_POS);
    int*   esrc = (int*)(ws + OFF_ESRC);
    int*   gst  = (int*)(ws + OFF_GST);
    int*   bsum = (int*)(ws + OFF_BSUM);
    int*   tot  = (int*)(ws + OFF_TOT);
    unsigned int* Hbf = (unsigned int*)(ws + OFF_HBF);

    // fused preamble: zero | wmask | bounds
    preamble_kernel<<<PRE_ZB + PRE_WB + PRE_BB, 256, 0, stream>>>(
        (int*)(ws + OFF_ZERO), embedW, embedM, layerW, layerM, wmT, gid, gst);
    // CSR build
    hist_kernel<<<(N_EDGES + 255) / 256, 256, 0, stream>>>(dst, deg, N_EDGES);
    scan1_kernel<<<SCAN_B, 256, 0, stream>>>(deg, offs, bsum, N_NODES);
    scan2_kernel<<<1, 256, 0, stream>>>(bsum, tot, SCAN_B);
    scan3_kernel<<<SCAN_B, 256, 0, stream>>>(offs, bsum, tot, pos, N_NODES);
    fill_kernel<<<(N_EDGES + 255) / 256, 256, 0, stream>>>(src, dst, pos, esrc, N_EDGES);

    // embedding: H = h0 @ (embed_W*mask)^T + embed_b  (+ bf16 copy)
    gemm_kernel<<<GEMM_GRID, 128, 0, stream>>>(h0, wmT, embedB, nullptr, H, nullptr,
                                               Hbf, N_NODES);

    const int agg_grid = (N_NODES / 2 + 3) / 4;
    for (int l = 0; l < N_LAYERS; ++l) {
        aggregate_kernel<<<agg_grid, 256, 0, stream>>>(Hbf, offs, esrc, AGG, N_NODES);
        gemm_kernel<<<GEMM_GRID, 128, 0, stream>>>(AGG, wmT + (1 + l) * 16384,
                                                   layerB + l * 128, snorm,
                                                   Z, csum + l * 256, nullptr, N_NODES);
        apply_kernel<<<(N_NODES * HID / 4) / 256, 256, 0, stream>>>(
            Z, csum, gamma, beta, H, Hbf, N_NODES * HID / 4, l);
    }

    readout2_kernel<<<N_GRAPHS * RSPLIT, 256, 0, stream>>>(H, gst, sums);
    final_kernel<<<N_GRAPHS, 128, 0, stream>>>(sums, gst, roW, rob, out);
}

// Round 11
// 515.089 us; speedup vs baseline: 1.4720x; 1.1514x over previous
//
#include <hip/hip_runtime.h>
#include <hip/hip_bf16.h>

#define N_NODES   50000
#define N_EDGES   600000
#define HID       128
#define N_LAYERS  4
#define N_GRAPHS  128
#define N_CLASSES 10
#define BN_EPS    1e-5f

#define TILE_R 64           // 8 ty-groups x 8 interleaved rows (r = ty + 8i)
#define KC     32
#define RSPLIT 8
#define SCAN_B 196          // ceil(50000/256)
#define GEMM_GRID ((N_NODES + TILE_R - 1) / TILE_R)   // 782

// ---------------- workspace layout (in 4-byte elements) ----------------
#define OFF_WMT   0u                         // 5 * 16384 masked+transposed weights [k][c]
#define OFF_H     81920u                     // 50000*128 fp32
#define OFF_Z     (OFF_H   + 6400000u)
#define OFF_AGG   (OFF_Z   + 6400000u)       // aggregate output [50000][128]
#define OFF_ZERO  (OFF_AGG + 6400000u)       // start of zero-initialized region
#define OFF_CSUM  OFF_ZERO                   // [4][2][128] = 1024 f
#define OFF_SUMS  (OFF_CSUM + 1024u)         // [128][128]  = 16384 f
#define OFF_DEG   (OFF_SUMS + 16384u)        // [50000] int
#define ZERO_N    (1024u + 16384u + 50000u)  // 67408 elements
#define OFF_OFFS  (OFF_ZERO + ZERO_N)        // [50001] int (padded to 50004)
#define OFF_POS   (OFF_OFFS + 50004u)        // [50000] int
#define OFF_ESRC  (OFF_POS  + 50000u)        // [600000] int
#define OFF_GST   (OFF_ESRC + 600000u)       // [129] int graph boundaries (pad 132)
#define OFF_BSUM  (OFF_GST  + 132u)          // [196] int block sums
#define OFF_TOT   (OFF_BSUM + 196u)          // [1] int total
#define OFF_HBF   (OFF_TOT  + 4u)            // [50000][128] bf16 = 3.2M u32

// preamble block ranges
#define PRE_ZB 264
#define PRE_WB 320
#define PRE_BB 196

// bf16 helpers (RNE)
__device__ __forceinline__ unsigned int bf16_of(float f) {
    unsigned int u = __float_as_uint(f);
    return (u + 0x7fffu + ((u >> 16) & 1u)) >> 16;
}
__device__ __forceinline__ unsigned int pack_bf2(float lo, float hi) {
    return bf16_of(lo) | (bf16_of(hi) << 16);
}

// fused preamble: zero workspace region | masked+transposed weights | graph bounds
__global__ __launch_bounds__(256) void preamble_kernel(
    int* __restrict__ zbase,
    const float* __restrict__ We, const float* __restrict__ Me,
    const float* __restrict__ Wl, const float* __restrict__ Ml,
    float* __restrict__ WmT,
    const int* __restrict__ gid, int* __restrict__ g_start)
{
    int b = blockIdx.x;
    if (b < PRE_ZB) {
        int i = b * 256 + threadIdx.x;
        if (i < (int)ZERO_N) zbase[i] = 0;
    } else if (b < PRE_ZB + PRE_WB) {
        int i = (b - PRE_ZB) * 256 + threadIdx.x;
        if (i < 5 * 16384) {
            int m = i >> 14;
            int j = i & 16383;
            int c = j >> 7, k = j & 127;
            float w, msk;
            if (m == 0) { w = We[j]; msk = Me[j]; }
            else        { w = Wl[(m - 1) * 16384 + j]; msk = Ml[(m - 1) * 16384 + j]; }
            WmT[m * 16384 + k * 128 + c] = w * msk;
        }
    } else {
        int i = (b - PRE_ZB - PRE_WB) * 256 + threadIdx.x;
        if (i >= N_NODES) return;
        int g = gid[i];
        if (i == 0) {
            for (int x = 0; x <= g; ++x) g_start[x] = 0;
        } else {
            int gp = gid[i - 1];
            for (int x = gp + 1; x <= g; ++x) g_start[x] = i;
        }
        if (i == N_NODES - 1) {
            for (int x = g + 1; x <= N_GRAPHS; ++x) g_start[x] = N_NODES;
        }
    }
}

__global__ __launch_bounds__(256) void hist_kernel(const int* __restrict__ dst,
                                                   int* __restrict__ deg, int nE) {
    int i = blockIdx.x * 256 + threadIdx.x;
    if (i < nE) atomicAdd(&deg[dst[i]], 1);
}

__global__ __launch_bounds__(256) void scan1_kernel(const int* __restrict__ deg,
                                                    int* __restrict__ off,
                                                    int* __restrict__ bsum, int n) {
    __shared__ int s[256];
    int tid = threadIdx.x;
    int i = blockIdx.x * 256 + tid;
    int v = (i < n) ? deg[i] : 0;
    s[tid] = v;
    __syncthreads();
#pragma unroll
    for (int ofs = 1; ofs < 256; ofs <<= 1) {
        int t = (tid >= ofs) ? s[tid - ofs] : 0;
        __syncthreads();
        s[tid] += t;
        __syncthreads();
    }
    if (i < n) off[i] = s[tid] - v;
    if (tid == 255) bsum[blockIdx.x] = s[255];
}

__global__ __launch_bounds__(256) void scan2_kernel(int* __restrict__ bsum,
                                                    int* __restrict__ total, int nb) {
    __shared__ int s[256];
    int tid = threadIdx.x;
    int v = (tid < nb) ? bsum[tid] : 0;
    s[tid] = v;
    __syncthreads();
#pragma unroll
    for (int ofs = 1; ofs < 256; ofs <<= 1) {
        int t = (tid >= ofs) ? s[tid - ofs] : 0;
        __syncthreads();
        s[tid] += t;
        __syncthreads();
    }
    if (tid < nb) bsum[tid] = s[tid] - v;
    if (tid == 255) *total = s[255];
}

__global__ __launch_bounds__(256) void scan3_kernel(int* __restrict__ off,
                                                    const int* __restrict__ bsum,
                                                    const int* __restrict__ total,
                                                    int* __restrict__ pos, int n) {
    int i = blockIdx.x * 256 + threadIdx.x;
    if (i < n) {
        int o = off[i] + bsum[blockIdx.x];
        off[i] = o;
        pos[i] = o;
    }
    if (i == 0) off[n] = *total;
}

__global__ __launch_bounds__(256) void fill_kernel(const int* __restrict__ src,
                                                   const int* __restrict__ dst,
                                                   int* __restrict__ pos,
                                                   int* __restrict__ esrc, int nE) {
    int i = blockIdx.x * 256 + threadIdx.x;
    if (i < nE) {
        int p = atomicAdd(&pos[dst[i]], 1);
        esrc[p] = src[i];
    }
}

// agg[n][:] = sum over incoming edges of Hbf[src][:]  (bf16 rows, fp32 accumulate)
__global__ __launch_bounds__(256) void aggregate_kernel(const unsigned int* __restrict__ Hbf,
                                                        const int* __restrict__ off,
                                                        const int* __restrict__ esrc,
                                                        float* __restrict__ agg, int nN) {
    int wid  = (blockIdx.x * 256 + threadIdx.x) >> 6;
    int lane = threadIdx.x & 63;
    int half = lane >> 5;
    int l4   = lane & 31;
    int node = wid * 2 + half;
    if (node >= nN) return;
    int beg = off[node], end = off[node + 1];
    const uint2* H2 = (const uint2*)Hbf;      // 32 uint2 per row (4 bf16 each)
    float4 a0 = make_float4(0.f, 0.f, 0.f, 0.f);
    float4 a1 = make_float4(0.f, 0.f, 0.f, 0.f);
    float4 a2 = make_float4(0.f, 0.f, 0.f, 0.f);
    float4 a3 = make_float4(0.f, 0.f, 0.f, 0.f);
#define ACCUM(AX, V)                                                        \
    AX.x += __uint_as_float((V).x << 16);                                   \
    AX.y += __uint_as_float((V).x & 0xffff0000u);                           \
    AX.z += __uint_as_float((V).y << 16);                                   \
    AX.w += __uint_as_float((V).y & 0xffff0000u);
    int e = beg;
    for (; e + 7 < end; e += 8) {
        int s0 = esrc[e],     s1 = esrc[e + 1], s2 = esrc[e + 2], s3 = esrc[e + 3];
        int s4 = esrc[e + 4], s5 = esrc[e + 5], s6 = esrc[e + 6], s7 = esrc[e + 7];
        uint2 v0 = H2[(size_t)s0 * 32 + l4];
        uint2 v1 = H2[(size_t)s1 * 32 + l4];
        uint2 v2 = H2[(size_t)s2 * 32 + l4];
        uint2 v3 = H2[(size_t)s3 * 32 + l4];
        uint2 v4 = H2[(size_t)s4 * 32 + l4];
        uint2 v5 = H2[(size_t)s5 * 32 + l4];
        uint2 v6 = H2[(size_t)s6 * 32 + l4];
        uint2 v7 = H2[(size_t)s7 * 32 + l4];
        ACCUM(a0, v0) ACCUM(a1, v1) ACCUM(a2, v2) ACCUM(a3, v3)
        ACCUM(a0, v4) ACCUM(a1, v5) ACCUM(a2, v6) ACCUM(a3, v7)
    }
    for (; e + 3 < end; e += 4) {
        int s0 = esrc[e], s1 = esrc[e + 1], s2 = esrc[e + 2], s3 = esrc[e + 3];
        uint2 v0 = H2[(size_t)s0 * 32 + l4];
        uint2 v1 = H2[(size_t)s1 * 32 + l4];
        uint2 v2 = H2[(size_t)s2 * 32 + l4];
        uint2 v3 = H2[(size_t)s3 * 32 + l4];
        ACCUM(a0, v0) ACCUM(a1, v1) ACCUM(a2, v2) ACCUM(a3, v3)
    }
    for (; e < end; ++e) {
        uint2 v0 = H2[(size_t)esrc[e] * 32 + l4];
        ACCUM(a0, v0)
    }
#undef ACCUM
    a0.x += a1.x; a0.y += a1.y; a0.z += a1.z; a0.w += a1.w;
    a2.x += a3.x; a2.y += a3.y; a2.z += a3.z; a2.w += a3.w;
    a0.x += a2.x; a0.y += a2.y; a0.z += a2.z; a0.w += a2.w;
    ((float4*)agg)[(size_t)node * 32 + l4] = a0;
}

// GEMM (R8-proven): 128 threads, 64 rows x 128 cols, 8 interleaved rows/thread.
// HBF=true instantiation additionally emits bf16 output rows (embedding only);
// HBF=false compiles with no hbf code -> low VGPR for the 4 layer calls.
template <bool HBF>
__global__ __launch_bounds__(128) void gemm_kernel(
    const float* __restrict__ A, const float* __restrict__ WmT,
    const float* __restrict__ bias, const float* __restrict__ snorm,
    float* __restrict__ Z, float* __restrict__ colsum,
    unsigned int* __restrict__ hbf, int nRows)
{
    __shared__ float4 As4[TILE_R * 9];        // [64][9] f4 rows (8 data + 1 pad)
    __shared__ float  Ws[KC][128];
    int tid = threadIdx.x;
    int tx = tid & 15;
    int ty = tid >> 4;                        // 8 row groups
    int r0 = blockIdx.x * TILE_R;
    const float4* A4 = (const float4*)A;

    float acc[8][8];
#pragma unroll
    for (int i = 0; i < 8; ++i)
#pragma unroll
        for (int j = 0; j < 8; ++j) acc[i][j] = 0.f;

    for (int c = 0; c < 4; ++c) {
        if (c) __syncthreads();
        {
            const float4* W4 = (const float4*)(WmT + c * KC * 128);
            float4* Wd = (float4*)&Ws[0][0];
#pragma unroll
            for (int it = 0; it < 8; ++it) Wd[tid + it * 128] = W4[tid + it * 128];
        }
        {
#pragma unroll
            for (int it = 0; it < 4; ++it) {
                int e = tid + it * 128;
                int r = e >> 3, g = e & 7;
                int gr = r0 + r;
                if (gr >= nRows) gr = nRows - 1;
                As4[r * 9 + g] = A4[(size_t)gr * 32 + c * 8 + g];
            }
        }
        __syncthreads();
#pragma unroll
        for (int q = 0; q < 8; ++q) {
            float4 av[8];
#pragma unroll
            for (int i = 0; i < 8; ++i)
                av[i] = As4[(ty + 8 * i) * 9 + q];
            const float* avf = (const float*)av;
#pragma unroll
            for (int j = 0; j < 4; ++j) {
                float4 w0 = *(const float4*)&Ws[q * 4 + j][tx * 4];
                float4 w1 = *(const float4*)&Ws[q * 4 + j][64 + tx * 4];
#pragma unroll
                for (int i = 0; i < 8; ++i) {
                    float a = avf[i * 4 + j];
                    acc[i][0] += a * w0.x; acc[i][1] += a * w0.y;
                    acc[i][2] += a * w0.z; acc[i][3] += a * w0.w;
                    acc[i][4] += a * w1.x; acc[i][5] += a * w1.y;
                    acc[i][6] += a * w1.z; acc[i][7] += a * w1.w;
                }
            }
        }
    }
    __syncthreads();

    int c0 = tx * 4;
    float bl[8];
#pragma unroll
    for (int j = 0; j < 4; ++j) {
        bl[j]     = bias[c0 + j];
        bl[4 + j] = bias[64 + c0 + j];
    }
    float cs[8], cq[8];
#pragma unroll
    for (int j = 0; j < 8; ++j) { cs[j] = 0.f; cq[j] = 0.f; }

#pragma unroll
    for (int i = 0; i < 8; ++i) {
        int r = r0 + ty + 8 * i;
        if (r < nRows) {
            float sn = snorm ? snorm[r] : 1.0f;
            float4 o0, o1;
            float v;
            v = (acc[i][0] + bl[0]) * sn; o0.x = v; cs[0] += v; cq[0] += v * v;
            v = (acc[i][1] + bl[1]) * sn; o0.y = v; cs[1] += v; cq[1] += v * v;
            v = (acc[i][2] + bl[2]) * sn; o0.z = v; cs[2] += v; cq[2] += v * v;
            v = (acc[i][3] + bl[3]) * sn; o0.w = v; cs[3] += v; cq[3] += v * v;
            v = (acc[i][4] + bl[4]) * sn; o1.x = v; cs[4] += v; cq[4] += v * v;
            v = (acc[i][5] + bl[5]) * sn; o1.y = v; cs[5] += v; cq[5] += v * v;
            v = (acc[i][6] + bl[6]) * sn; o1.z = v; cs[6] += v; cq[6] += v * v;
            v = (acc[i][7] + bl[7]) * sn; o1.w = v; cs[7] += v; cq[7] += v * v;
            *(float4*)(Z + (size_t)r * 128 + c0)      = o0;
            *(float4*)(Z + (size_t)r * 128 + 64 + c0) = o1;
            if (HBF) {
                hbf[(size_t)r * 64 + tx * 2]      = pack_bf2(o0.x, o0.y);
                hbf[(size_t)r * 64 + tx * 2 + 1]  = pack_bf2(o0.z, o0.w);
                hbf[(size_t)r * 64 + 32 + tx * 2]     = pack_bf2(o1.x, o1.y);
                hbf[(size_t)r * 64 + 32 + tx * 2 + 1] = pack_bf2(o1.z, o1.w);
            }
        }
    }

    if (colsum) {
        float* red = &Ws[0][0];
        for (int round = 0; round < 2; ++round) {
            float* srcp = round ? cq : cs;
#pragma unroll
            for (int j = 0; j < 4; ++j) {
                red[ty * 128 + c0 + j]      = srcp[j];
                red[ty * 128 + 64 + c0 + j] = srcp[4 + j];
            }
            __syncthreads();
            {
                float s = 0.f;
#pragma unroll
                for (int t = 0; t < 8; ++t) s += red[t * 128 + tid];
                atomicAdd(&colsum[round * 128 + tid], s);
            }
            __syncthreads();
        }
    }
}

// H += relu(BN(Z)); also emit bf16 H copy for the next layer's gather
__global__ __launch_bounds__(256) void apply_kernel(const float* __restrict__ Z,
                                                    const float* __restrict__ csum,
                                                    const float* __restrict__ gamma,
                                                    const float* __restrict__ beta,
                                                    float* __restrict__ H,
                                                    unsigned int* __restrict__ hbf,
                                                    int n4, int layer) {
    int i = blockIdx.x * 256 + threadIdx.x;
    if (i >= n4) return;
    int c4 = i & 31;
    const float invN = 1.0f / (float)N_NODES;
    float4 s  = ((const float4*)(csum  + layer * 256))[c4];
    float4 q  = ((const float4*)(csum  + layer * 256 + 128))[c4];
    float4 g  = ((const float4*)(gamma + layer * 128))[c4];
    float4 be = ((const float4*)(beta  + layer * 128))[c4];
    float4 z = ((const float4*)Z)[i];
    float4 h = ((float4*)H)[i];
    float mu, var, sc, sh;
    mu = s.x * invN; var = q.x * invN - mu * mu; sc = g.x * rsqrtf(var + BN_EPS); sh = be.x - mu * sc;
    h.x += fmaxf(z.x * sc + sh, 0.f);
    mu = s.y * invN; var = q.y * invN - mu * mu; sc = g.y * rsqrtf(var + BN_EPS); sh = be.y - mu * sc;
    h.y += fmaxf(z.y * sc + sh, 0.f);
    mu = s.z * invN; var = q.z * invN - mu * mu; sc = g.z * rsqrtf(var + BN_EPS); sh = be.z - mu * sc;
    h.z += fmaxf(z.z * sc + sh, 0.f);
    mu = s.w * invN; var = q.w * invN - mu * mu; sc = g.w * rsqrtf(var + BN_EPS); sh = be.w - mu * sc;
    h.w += fmaxf(z.w * sc + sh, 0.f);
    ((float4*)H)[i] = h;
    hbf[i * 2]     = pack_bf2(h.x, h.y);
    hbf[i * 2 + 1] = pack_bf2(h.z, h.w);
}

// dense per-graph reduction using sorted-gid boundaries (fp32 H)
__global__ __launch_bounds__(256) void readout2_kernel(const float* __restrict__ H,
                                                       const int* __restrict__ g_start,
                                                       float* __restrict__ sums) {
    int g     = blockIdx.x / RSPLIT;
    int chunk = blockIdx.x % RSPLIT;
    int beg = g_start[g], end = g_start[g + 1];
    int col  = threadIdx.x & 127;
    int half = threadIdx.x >> 7;
    float acc = 0.f;
    for (int r = beg + chunk * 2 + half; r < end; r += RSPLIT * 2) {
        acc += H[(size_t)r * 128 + col];
    }
    if (acc != 0.f || half == 0)
        atomicAdd(&sums[g * 128 + col], acc);
}

__global__ __launch_bounds__(128) void final_kernel(const float* __restrict__ sums,
                                                    const int* __restrict__ g_start,
                                                    const float* __restrict__ roW,
                                                    const float* __restrict__ rob,
                                                    float* __restrict__ out) {
    __shared__ float row[128];
    int g = blockIdx.x;
    int t = threadIdx.x;
    float c = fmaxf((float)(g_start[g + 1] - g_start[g]), 1.0f);
    row[t] = sums[g * 128 + t] / c;
    __syncthreads();
    if (t < N_CLASSES) {
        float s = rob[t];
        for (int k = 0; k < 128; ++k) s += row[k] * roW[t * 128 + k];
        out[g * N_CLASSES + t] = s;
    }
}

extern "C" void kernel_launch(void* const* d_in, const int* in_sizes, int n_in,
                              void* d_out, int out_size, void* d_ws, size_t ws_size,
                              hipStream_t stream) {
    const float* h0      = (const float*)d_in[0];
    const float* snorm   = (const float*)d_in[1];
    const int*   src     = (const int*)d_in[2];
    const int*   dst     = (const int*)d_in[3];
    const int*   gid     = (const int*)d_in[4];
    const float* embedW  = (const float*)d_in[5];
    const float* embedM  = (const float*)d_in[6];
    const float* embedB  = (const float*)d_in[7];
    const float* layerW  = (const float*)d_in[8];
    const float* layerM  = (const float*)d_in[9];
    const float* layerB  = (const float*)d_in[10];
    const float* gamma   = (const float*)d_in[11];
    const float* beta    = (const float*)d_in[12];
    const float* roW     = (const float*)d_in[13];
    const float* rob     = (const float*)d_in[14];
    float* out = (float*)d_out;

    float* ws   = (float*)d_ws;
    float* wmT  = ws + OFF_WMT;
    float* H    = ws + OFF_H;
    float* Z    = ws + OFF_Z;
    float* AGG  = ws + OFF_AGG;
    float* csum = ws + OFF_CSUM;
    float* sums = ws + OFF_SUMS;
    int*   deg  = (int*)(ws + OFF_DEG);
    int*   offs = (int*)(ws + OFF_OFFS);
    int*   pos  = (int*)(ws + OFF_POS);
    int*   esrc = (int*)(ws + OFF_ESRC);
    int*   gst  = (int*)(ws + OFF_GST);
    int*   bsum = (int*)(ws + OFF_BSUM);
    int*   tot  = (int*)(ws + OFF_TOT);
    unsigned int* Hbf = (unsigned int*)(ws + OFF_HBF);

    // fused preamble: zero | wmask | bounds
    preamble_kernel<<<PRE_ZB + PRE_WB + PRE_BB, 256, 0, stream>>>(
        (int*)(ws + OFF_ZERO), embedW, embedM, layerW, layerM, wmT, gid, gst);
    // CSR build
    hist_kernel<<<(N_EDGES + 255) / 256, 256, 0, stream>>>(dst, deg, N_EDGES);
    scan1_kernel<<<SCAN_B, 256, 0, stream>>>(deg, offs, bsum, N_NODES);
    scan2_kernel<<<1, 256, 0, stream>>>(bsum, tot, SCAN_B);
    scan3_kernel<<<SCAN_B, 256, 0, stream>>>(offs, bsum, tot, pos, N_NODES);
    fill_kernel<<<(N_EDGES + 255) / 256, 256, 0, stream>>>(src, dst, pos, esrc, N_EDGES);

    // embedding: H = h0 @ (embed_W*mask)^T + embed_b  (+ bf16 copy)
    gemm_kernel<true><<<GEMM_GRID, 128, 0, stream>>>(h0, wmT, embedB, nullptr, H, nullptr,
                                                     Hbf, N_NODES);

    const int agg_grid = (N_NODES / 2 + 3) / 4;
    for (int l = 0; l < N_LAYERS; ++l) {
        aggregate_kernel<<<agg_grid, 256, 0, stream>>>(Hbf, offs, esrc, AGG, N_NODES);
        gemm_kernel<false><<<GEMM_GRID, 128, 0, stream>>>(AGG, wmT + (1 + l) * 16384,
                                                          layerB + l * 128, snorm,
                                                          Z, csum + l * 256, nullptr, N_NODES);
        apply_kernel<<<(N_NODES * HID / 4) / 256, 256, 0, stream>>>(
            Z, csum, gamma, beta, H, Hbf, N_NODES * HID / 4, l);
    }

    readout2_kernel<<<N_GRAPHS * RSPLIT, 256, 0, stream>>>(H, gst, sums);
    final_kernel<<<N_GRAPHS, 128, 0, stream>>>(sums, gst, roW, rob, out);
}